// Round 16
// baseline (633.303 us; speedup 1.0000x reference)
//
#include <hip/hip_runtime.h>
#include <hip/hip_bf16.h>
#include <hip/hip_fp8.h>
#include <stdint.h>

// x: (4,4096,1024) f32 -> 16384 x 1024 rows; codebook: (16384,1024) f32
#define NROWS  16384
#define NCODES 16384
#define DIM    1024
#define NT     16           // DIM / BK,  BK = 64
#define MARGIN_Q 514        // fp8 path: 32.1 in 1/16 units (~9 sigma of fp8 score noise)

typedef float f32x4   __attribute__((ext_vector_type(4)));
typedef float f32x16  __attribute__((ext_vector_type(16)));
typedef int   i32x4   __attribute__((ext_vector_type(4)));
typedef int   i32x8   __attribute__((ext_vector_type(8)));
typedef short bf16x8  __attribute__((ext_vector_type(8)));
typedef unsigned char uchar;

__device__ __forceinline__ ushort f2bf(float f) {
  uint32_t u = __float_as_uint(f);
  uint32_t r = u + 0x7FFFu + ((u >> 16) & 1u);
  return (ushort)(r >> 16);
}
__device__ __forceinline__ int imin(int a, int b){ return a < b ? a : b; }
__device__ __forceinline__ int imax(int a, int b){ return a < b ? b : a; }
__device__ __forceinline__ int packKey32(float s, int idx) {
  int q = (int)rintf(s * 16.0f);
  return q * 16384 + idx;
}

#define GLDS16(gp, lp) \
  __builtin_amdgcn_global_load_lds((const __attribute__((address_space(1))) void*)(gp), \
                                   (__attribute__((address_space(3))) void*)(lp), 16, 0, 0)

__device__ __forceinline__ void sbar() {
  asm volatile("" ::: "memory");
  __builtin_amdgcn_s_barrier();
  asm volatile("" ::: "memory");
}

// ---------------- kernel 0: c2[c] = sum(codebook[c]^2) (exact f32) ----------------
__global__ __launch_bounds__(256) void c2_kernel(const float* __restrict__ cb,
                                                 float* __restrict__ c2) {
  const int code = blockIdx.x;
  const int t = threadIdx.x, lane = t & 63, wid = t >> 6;
  f32x4 v = *(const f32x4*)(cb + (size_t)code * DIM + t * 4);
  float s = v[0]*v[0] + v[1]*v[1] + v[2]*v[2] + v[3]*v[3];
  #pragma unroll
  for (int off = 32; off; off >>= 1) s += __shfl_down(s, off);
  __shared__ float part[4];
  if (lane == 0) part[wid] = s;
  __syncthreads();
  if (t == 0) c2[code] = part[0] + part[1] + part[2] + part[3];
}

// ---------------- kernel 0b: f32 -> fp8 e4m3, fragment-order 256x64-tile layout ----------------
// Tile (m,kt) = 16 KB. Chunk w in [0,1024): st=w>>7 (32-row subtile), h=(w>>6)&1
// (k-half), l=w&63 (lane). Content: row st*32+(l&31), k-bytes (l>>5)*32+h*16..+16.
// This IS the 32x32x64 f8f6f4 operand order (verified numerically: R11/R15 absmax 0).
__global__ __launch_bounds__(256) void convert_fp8_mx(const float* __restrict__ src,
                                                      uchar* __restrict__ dst) {
  const int c  = blockIdx.x * 256 + threadIdx.x;   // 16B chunk id, [0, 2^20)
  const int wch = c & 1023;
  const int st = wch >> 7;
  const int h  = (wch >> 6) & 1;
  const int l  = wch & 63;
  const int kt = (c >> 10) & 15;
  const int m  = c >> 14;
  const int row = st * 32 + (l & 31);
  const int kb  = (l >> 5) * 32 + h * 16;
  const float* s = src + (size_t)(m * 256 + row) * DIM + kt * 64 + kb;
  uint64_t lo = 0, hi = 0;
  #pragma unroll
  for (int j = 0; j < 8; ++j) {
    __hip_fp8_e4m3 a(s[j]);
    __hip_fp8_e4m3 b(s[j + 8]);
    lo |= (uint64_t)a.__x << (8 * j);
    hi |= (uint64_t)b.__x << (8 * j);
  }
  uint64_t* o = (uint64_t*)(dst + (size_t)c * 16);
  o[0] = lo; o[1] = hi;
}

// ---------------- kernel 1: 256^2 fp8 32x32x64 GEMM (AGPR acc), 3-deep rings + counted vmcnt ----------------
// R15 post-mortem: tile time ~4900 cyc vs ~1100 MFMA -> stall-bound, 1 block/CU
// resident (236 regs/wave), every vmcnt(0) exposed. Fix: stage 2 tiles ahead
// into 3-deep rings; guard vmcnt(4) drains only tile t+1's loads, keeps t+2's
// in flight (T4: never drain to 0 mid-loop). Ring-reuse hazard: stage (t+2)%3
// == (t-1)%3, whose reads drained at lgkm(0)+barrier of t-1.
#define STAGE_A(BUF, KT) do {                                                     \
    GLDS16(ga + (KT)*16384,        &lsA[BUF][w*1024]);                            \
    GLDS16(ga + (KT)*16384 + 8192, &lsA[BUF][w*1024 + 8192]);                     \
  } while (0)
#define STAGE_B(BUF, KT) do {                                                     \
    GLDS16(gb + (KT)*16384,        &lsB[BUF][w*1024]);                            \
    GLDS16(gb + (KT)*16384 + 8192, &lsB[BUF][w*1024 + 8192]);                     \
  } while (0)

#define RD_A(BUF) do {                                                            \
    _Pragma("unroll")                                                             \
    for (int mi_ = 0; mi_ < 4; ++mi_) {                                           \
      i32x4 lo_ = *(const i32x4*)(Abase[BUF] + mi_ * 2048);                       \
      i32x4 hi_ = *(const i32x4*)(Abase[BUF] + mi_ * 2048 + 1024);                \
      _Pragma("unroll")                                                           \
      for (int j_ = 0; j_ < 4; ++j_) { aF[mi_][j_] = lo_[j_]; aF[mi_][4+j_] = hi_[j_]; } \
    } } while (0)
#define RD_B(BUF) do {                                                            \
    _Pragma("unroll")                                                             \
    for (int nb_ = 0; nb_ < 2; ++nb_) {                                           \
      i32x4 lo_ = *(const i32x4*)(Bbase[BUF] + nb_ * 2048);                       \
      i32x4 hi_ = *(const i32x4*)(Bbase[BUF] + nb_ * 2048 + 1024);                \
      _Pragma("unroll")                                                           \
      for (int j_ = 0; j_ < 4; ++j_) { bF[nb_][j_] = lo_[j_]; bF[nb_][4+j_] = hi_[j_]; } \
    } } while (0)

#define MMA_ALL do {                                                              \
    __builtin_amdgcn_s_setprio(1);                                                \
    _Pragma("unroll")                                                             \
    for (int mi_ = 0; mi_ < 4; ++mi_) {                                           \
      _Pragma("unroll")                                                           \
      for (int nb_ = 0; nb_ < 2; ++nb_)                                           \
        asm("v_mfma_f32_32x32x64_f8f6f4 %0, %1, %2, %3"                           \
            : "=a"(acc[mi_][nb_])                                                 \
            : "v"(aF[mi_]), "v"(bF[nb_]), "0"(acc[mi_][nb_]));                    \
    }                                                                             \
    __builtin_amdgcn_s_setprio(0);                                                \
  } while (0)

#define G4  asm volatile("s_waitcnt vmcnt(4)" ::: "memory")
#define G0  asm volatile("s_waitcnt vmcnt(0)" ::: "memory")
#define NOG do {} while (0)

#define TILE(KT, CUR, NXT, DOST, GUARD) do {                                      \
    if (DOST) { STAGE_A(NXT, (KT) + 2); STAGE_B(NXT, (KT) + 2); }                 \
    RD_B(CUR);                                                                    \
    RD_A(CUR);                                                                    \
    MMA_ALL;                                                                      \
    asm volatile("s_waitcnt lgkmcnt(0)" ::: "memory");                            \
    GUARD;                                                                        \
    sbar();                                                                       \
  } while (0)

__global__ __launch_bounds__(512, 2) void snap_gemm256(const uchar* __restrict__ xs,
                                                       const uchar* __restrict__ cs,
                                                       const float* __restrict__ c2,
                                                       int* __restrict__ cand) {
  __shared__ uchar lsA[3][16384];   // 3-deep A ring (48 KB)
  __shared__ uchar lsB[3][16384];   // 3-deep B ring (48 KB) -> 96 KB

  const int t    = threadIdx.x;
  const int lane = t & 63;
  const int w    = t >> 6;          // 0..7
  const int wm   = w >> 2;          // 0..1  (rows wm*128..+128)
  const int wn   = w & 3;           // 0..3  (cols wn*64..+64)

  // XCD-aware swizzle (bijective: 4096 % 8 == 0)
  const int bid = blockIdx.x;
  const int swz = (bid & 7) * 512 + (bid >> 3);
  const int bm  = swz & 63;
  const int bn  = swz >> 6;

  const uchar* ga = xs + (size_t)bm * 16 * 16384 + w * 1024 + lane * 16;
  const uchar* gb = cs + (size_t)bn * 16 * 16384 + w * 1024 + lane * 16;

  // Fragment read bases: subtile*2048 + h*1024 + lane*16 (lane-stride 16B: bank-uniform).
  const uchar* Abase[3]; const uchar* Bbase[3];
  #pragma unroll
  for (int b = 0; b < 3; ++b) {
    Abase[b] = &lsA[b][wm * 8192 + lane * 16];
    Bbase[b] = &lsB[b][wn * 4096 + lane * 16];
  }

  f32x16 acc[4][2];
  #pragma unroll
  for (int mi = 0; mi < 4; ++mi)
    #pragma unroll
    for (int nb = 0; nb < 2; ++nb)
      #pragma unroll
      for (int r = 0; r < 16; ++r)
        acc[mi][nb][r] = 0.f;

  i32x8 aF[4], bF[2];

  // ---- prologue: tiles 0 and 1 (8 loads); drain tile 0's 4, keep tile 1's flying ----
  STAGE_A(0, 0); STAGE_B(0, 0);
  STAGE_A(1, 1); STAGE_B(1, 1);
  G4;
  sbar();

  // buf = kt%3; stage target (kt+2)%3. Guard vmcnt(4): drains tile (t+1)'s
  // loads, keeps tile (t+2)'s 4 in flight.
  TILE(0 , 0, 2, 1, G4);
  TILE(1 , 1, 0, 1, G4);
  TILE(2 , 2, 1, 1, G4);
  TILE(3 , 0, 2, 1, G4);
  TILE(4 , 1, 0, 1, G4);
  TILE(5 , 2, 1, 1, G4);
  TILE(6 , 0, 2, 1, G4);
  TILE(7 , 1, 0, 1, G4);
  TILE(8 , 2, 1, 1, G4);
  TILE(9 , 0, 2, 1, G4);
  TILE(10, 1, 0, 1, G4);
  TILE(11, 2, 1, 1, G4);
  TILE(12, 0, 2, 1, G4);
  TILE(13, 1, 0, 1, G4);
  TILE(14, 2, 1, 0, G0);
  TILE(15, 0, 1, 0, NOG);

  __syncthreads();   // full drain before overlaying redbuf on lsA

  // ---- epilogue: per-row top-2 over this block's 256 columns ----
  // C/D 32x32: col = lane&31, row_in = (reg&3) + 8*(reg>>2) + 4*(lane>>5).
  int* red = (int*)&lsA[0][0];   // [4][256][2] i32 = 8 KB
  const int colb = bn * 256 + wn * 64 + (lane & 31);
  const float c2v0 = c2[colb];
  const float c2v1 = c2[colb + 32];
  const int rbase = wm * 128 + 4 * (lane >> 5);

  #pragma unroll
  for (int mi = 0; mi < 4; ++mi) {
    #pragma unroll
    for (int reg = 0; reg < 16; ++reg) {
      int ka = packKey32(fmaf(-2.0f, acc[mi][0][reg], c2v0), colb);
      int kb = packKey32(fmaf(-2.0f, acc[mi][1][reg], c2v1), colb + 32);
      int k1 = imin(ka, kb), k2 = imax(ka, kb);
      #pragma unroll
      for (int m = 1; m < 32; m <<= 1) {
        int o1 = __shfl_xor(k1, m);
        int o2 = __shfl_xor(k2, m);
        int n1 = imin(k1, o1);
        int n2 = imin(imax(k1, o1), imin(k2, o2));
        k1 = n1; k2 = n2;
      }
      if ((lane & 31) == 0) {
        int row = rbase + mi * 32 + (reg & 3) + 8 * (reg >> 2);
        red[(wn * 256 + row) * 2 + 0] = k1;
        red[(wn * 256 + row) * 2 + 1] = k2;
      }
    }
  }
  __syncthreads();

  if (t < 256) {
    int k1 = red[(0 * 256 + t) * 2 + 0];
    int k2 = red[(0 * 256 + t) * 2 + 1];
    #pragma unroll
    for (int q = 1; q < 4; ++q) {
      int p1 = red[(q * 256 + t) * 2 + 0];
      int p2 = red[(q * 256 + t) * 2 + 1];
      int n1 = imin(k1, p1);
      int n2 = imin(imax(k1, p1), imin(k2, p2));
      k1 = n1; k2 = n2;
    }
    size_t o = (size_t)(bm * 256 + t) * 128 + (size_t)bn * 2;
    cand[o]     = k1;
    cand[o + 1] = k2;
  }
}

// ---------------- kernel 1 (fallback, known-good structure): on-the-fly bf16 128^2 ----------------
__global__ __launch_bounds__(256) void snap_gemm_slow(const float* __restrict__ x,
                                                      const float* __restrict__ cb,
                                                      const float* __restrict__ c2,
                                                      int* __restrict__ cand) {
  __shared__ ushort lsA[2][8192];
  __shared__ ushort lsB[2][8192];
  __shared__ int redbuf[2][128][2];

  const int t    = threadIdx.x;
  const int lane = t & 63;
  const int wid  = t >> 6;
  const int wm   = wid & 1;
  const int wn   = wid >> 1;
  const int l15  = lane & 15;
  const int kgrp = lane >> 4;

  const int bm = blockIdx.x & 127;
  const int bn = blockIdx.x >> 7;
  const int rowBase = bm * 128;
  const int colBase = bn * 128;

  const float* aptr[4];
  const float* bptr[4];
  int ldsOff[4];
  #pragma unroll
  for (int i = 0; i < 4; ++i) {
    int pc = t + 256 * i;
    int row = pc >> 3;
    int g = (pc & 7) ^ (row & 7);
    aptr[i] = x  + (size_t)(rowBase + row) * DIM + g * 8;
    bptr[i] = cb + (size_t)(colBase + row) * DIM + g * 8;
    ldsOff[i] = pc * 8;
  }

  f32x4 acc[4][4];
  #pragma unroll
  for (int mi = 0; mi < 4; ++mi)
    #pragma unroll
    for (int ni = 0; ni < 4; ++ni)
      acc[mi][ni] = (f32x4){0.f, 0.f, 0.f, 0.f};

  auto STAGE = [&](int buf, int kt) {
    const int kOff = kt * 64;
    #pragma unroll
    for (int i = 0; i < 4; ++i) {
      f32x4 a0 = *(const f32x4*)(aptr[i] + kOff);
      f32x4 a1 = *(const f32x4*)(aptr[i] + kOff + 4);
      f32x4 b0 = *(const f32x4*)(bptr[i] + kOff);
      f32x4 b1 = *(const f32x4*)(bptr[i] + kOff + 4);
      bf16x8 pa, pb;
      #pragma unroll
      for (int j = 0; j < 4; ++j) {
        pa[j]     = (short)f2bf(a0[j]);
        pa[j + 4] = (short)f2bf(a1[j]);
        pb[j]     = (short)f2bf(b0[j]);
        pb[j + 4] = (short)f2bf(b1[j]);
      }
      *(bf16x8*)(&lsA[buf][ldsOff[i]]) = pa;
      *(bf16x8*)(&lsB[buf][ldsOff[i]]) = pb;
    }
  };

  STAGE(0, 0);
  __syncthreads();

  for (int kt = 0; kt < DIM / 64; ++kt) {
    const int cur = kt & 1;
    if (kt < DIM / 64 - 1) STAGE(cur ^ 1, kt + 1);

    const ushort* bA = &lsA[cur][0];
    const ushort* bB = &lsB[cur][0];
    #pragma unroll
    for (int ks = 0; ks < 2; ++ks) {
      const int gidx = ks * 4 + kgrp;
      bf16x8 af[4], bfr[4];
      #pragma unroll
      for (int mi = 0; mi < 4; ++mi) {
        int r_ = wm * 64 + mi * 16 + l15;
        af[mi] = *(const bf16x8*)(bA + (r_ * 8 + (gidx ^ (r_ & 7))) * 8);
      }
      #pragma unroll
      for (int ni = 0; ni < 4; ++ni) {
        int c_ = wn * 64 + ni * 16 + l15;
        bfr[ni] = *(const bf16x8*)(bB + (c_ * 8 + (gidx ^ (c_ & 7))) * 8);
      }
      #pragma unroll
      for (int mi = 0; mi < 4; ++mi)
        #pragma unroll
        for (int ni = 0; ni < 4; ++ni)
          acc[mi][ni] = __builtin_amdgcn_mfma_f32_16x16x32_bf16(af[mi], bfr[ni], acc[mi][ni], 0, 0, 0);
    }
    __syncthreads();
  }

  float c2v[4];
  int   colv[4];
  #pragma unroll
  for (int ni = 0; ni < 4; ++ni) {
    colv[ni] = colBase + wn * 64 + ni * 16 + l15;
    c2v[ni]  = c2[colv[ni]];
  }

  #pragma unroll
  for (int mi = 0; mi < 4; ++mi) {
    #pragma unroll
    for (int r = 0; r < 4; ++r) {
      int a = packKey32(fmaf(-2.0f, acc[mi][0][r], c2v[0]), colv[0]);
      int b = packKey32(fmaf(-2.0f, acc[mi][1][r], c2v[1]), colv[1]);
      int c = packKey32(fmaf(-2.0f, acc[mi][2][r], c2v[2]), colv[2]);
      int d = packKey32(fmaf(-2.0f, acc[mi][3][r], c2v[3]), colv[3]);
      int lo1 = imin(a, b), hi1 = imax(a, b);
      int lo2 = imin(c, d), hi2 = imax(c, d);
      int k1 = imin(lo1, lo2);
      int k2 = imin(imax(lo1, lo2), imin(hi1, hi2));
      #pragma unroll
      for (int m = 1; m < 16; m <<= 1) {
        int o1 = __shfl_xor(k1, m);
        int o2 = __shfl_xor(k2, m);
        int n1 = imin(k1, o1);
        int n2 = imin(imax(k1, o1), imin(k2, o2));
        k1 = n1; k2 = n2;
      }
      if (l15 == 0) {
        int rl = wm * 64 + mi * 16 + kgrp * 4 + r;
        redbuf[wn][rl][0] = k1;
        redbuf[wn][rl][1] = k2;
      }
    }
  }
  __syncthreads();

  if (t < 128) {
    int a1 = redbuf[0][t][0], a2 = redbuf[0][t][1];
    int b1 = redbuf[1][t][0], b2 = redbuf[1][t][1];
    int m1 = imin(a1, b1);
    int m2 = imin(imax(a1, b1), imin(a2, b2));
    size_t o = (size_t)(rowBase + t) * 256 + (size_t)bn * 2;
    cand[o]     = m1;
    cand[o + 1] = m2;
  }
}

// ---------------- kernel 2: exact f64 rerank of candidates within margin of pool-min ----------------
__global__ __launch_bounds__(256) void rerank(const float* __restrict__ x,
                                              const float* __restrict__ cb,
                                              const int* __restrict__ cand,
                                              int* __restrict__ bestidx,
                                              int poolN) {
  const int row = blockIdx.x;
  const int t = threadIdx.x, lane = t & 63, wid = t >> 6;
  __shared__ int    smin[4];
  __shared__ int    gshared;
  __shared__ double dpart[4];
  __shared__ int    cnt;
  __shared__ int    list[64];

  int my = (t < poolN) ? cand[(size_t)row * poolN + t] : 0x7FFFFFFF;
  int k = my;
  #pragma unroll
  for (int off = 32; off; off >>= 1) k = imin(k, __shfl_down(k, off));
  if (lane == 0) smin[wid] = k;
  if (t == 0) cnt = 0;
  __syncthreads();
  if (t == 0) {
    int g = smin[0];
    for (int i = 1; i < 4; ++i) g = imin(g, smin[i]);
    gshared = g;
  }
  __syncthreads();

  const int gq = gshared >> 14;
  if ((my >> 14) <= gq + MARGIN_Q) {
    int p = atomicAdd(&cnt, 1);
    if (p < 64) list[p] = my & 16383;
  }
  __syncthreads();
  int n = cnt; if (n > 64) n = 64;

  uint64_t best = ~0ull;
  const float* xr = x + (size_t)row * DIM;
  for (int i = 0; i < n; ++i) {
    const int cidx = list[i];
    const float* cr = cb + (size_t)cidx * DIM;
    double p = 0.0;
    #pragma unroll
    for (int j = 0; j < 4; ++j) {
      int d = t + 256 * j;
      double diff = (double)xr[d] - (double)cr[d];
      p += diff * diff;
    }
    #pragma unroll
    for (int off = 32; off; off >>= 1) p += __shfl_down(p, off);
    if (lane == 0) dpart[wid] = p;
    __syncthreads();
    if (t == 0) {
      double d2 = dpart[0] + dpart[1] + dpart[2] + dpart[3];
      uint64_t bits = (uint64_t)__double_as_longlong(d2);
      uint64_t key = (bits & ~0x3FFFull) | (uint32_t)cidx;
      if (key < best) best = key;
    }
    __syncthreads();
  }
  if (t == 0) bestidx[row] = (int)(best & 0x3FFFull);
}

// ---------------- kernel 3: gather winning codebook rows ----------------
__global__ __launch_bounds__(256) void gather_rows(const float* __restrict__ cb,
                                                   const int* __restrict__ bestidx,
                                                   float* __restrict__ out) {
  const int row = blockIdx.x;
  const int idx = bestidx[row];
  f32x4 v = *(const f32x4*)(cb + (size_t)idx * DIM + threadIdx.x * 4);
  *(f32x4*)(out + (size_t)row * DIM + threadIdx.x * 4) = v;
}

extern "C" void kernel_launch(void* const* d_in, const int* in_sizes, int n_in,
                              void* d_out, int out_size, void* d_ws, size_t ws_size,
                              hipStream_t stream) {
  const float* x  = (const float*)d_in[0];
  const float* cb = (const float*)d_in[1];
  float* out = (float*)d_out;

  float* c2      = (float*)d_ws;                        // 64 KB
  int*   bestidx = (int*)((char*)d_ws + 64 * 1024);     // 64 KB

  const size_t candBytes = (size_t)NROWS * 128 * 4;     // 8 MB (32-bit keys)
  const size_t needFast  = 128 * 1024 + candBytes;

  c2_kernel<<<NCODES, 256, 0, stream>>>(cb, c2);

  if (ws_size >= needFast) {
    uchar* xs = (uchar*)d_out;                          // 16.8 MB fp8, fragment-order
    uchar* cs = xs + (size_t)NROWS * DIM;               // 16.8 MB
    int* cand = (int*)((char*)d_ws + 128 * 1024);

    convert_fp8_mx<<<4096, 256, 0, stream>>>(x,  xs);
    convert_fp8_mx<<<4096, 256, 0, stream>>>(cb, cs);
    snap_gemm256<<<4096, 512, 0, stream>>>(xs, cs, c2, cand);
    rerank<<<NROWS, 256, 0, stream>>>(x, cb, cand, bestidx, 128);
    gather_rows<<<NROWS, 256, 0, stream>>>(cb, bestidx, out);
  } else {
    int* cand = (int*)d_out;
    snap_gemm_slow<<<(NROWS / 128) * (NCODES / 128), 256, 0, stream>>>(x, cb, c2, cand);
    rerank<<<NROWS, 256, 0, stream>>>(x, cb, cand, bestidx, 256);
    gather_rows<<<NROWS, 256, 0, stream>>>(cb, bestidx, out);
  }
}

// Round 17
// 629.147 us; speedup vs baseline: 1.0066x; 1.0066x over previous
//
#include <hip/hip_runtime.h>
#include <hip/hip_bf16.h>
#include <hip/hip_fp8.h>
#include <stdint.h>

// x: (4,4096,1024) f32 -> 16384 x 1024 rows; codebook: (16384,1024) f32
#define NROWS  16384
#define NCODES 16384
#define DIM    1024
#define NT     16           // DIM / BK,  BK = 64
#define MARGIN_Q 514        // fp8 path: 32.1 in 1/16 units (~9 sigma of fp8 score noise)

typedef float f32x4   __attribute__((ext_vector_type(4)));
typedef float f32x16  __attribute__((ext_vector_type(16)));
typedef int   i32x4   __attribute__((ext_vector_type(4)));
typedef int   i32x8   __attribute__((ext_vector_type(8)));
typedef short bf16x8  __attribute__((ext_vector_type(8)));
typedef unsigned char uchar;

__device__ __forceinline__ ushort f2bf(float f) {
  uint32_t u = __float_as_uint(f);
  uint32_t r = u + 0x7FFFu + ((u >> 16) & 1u);
  return (ushort)(r >> 16);
}
__device__ __forceinline__ int imin(int a, int b){ return a < b ? a : b; }
__device__ __forceinline__ int imax(int a, int b){ return a < b ? b : a; }
__device__ __forceinline__ int packKey32(float s, int idx) {
  int q = (int)rintf(s * 16.0f);
  return q * 16384 + idx;
}

#define GLDS16(gp, lp) \
  __builtin_amdgcn_global_load_lds((const __attribute__((address_space(1))) void*)(gp), \
                                   (__attribute__((address_space(3))) void*)(lp), 16, 0, 0)

__device__ __forceinline__ void sbar() {
  asm volatile("" ::: "memory");
  __builtin_amdgcn_s_barrier();
  asm volatile("" ::: "memory");
}

// ---------------- kernel 0: c2[c] = sum(codebook[c]^2) (exact f32) ----------------
__global__ __launch_bounds__(256) void c2_kernel(const float* __restrict__ cb,
                                                 float* __restrict__ c2) {
  const int code = blockIdx.x;
  const int t = threadIdx.x, lane = t & 63, wid = t >> 6;
  f32x4 v = *(const f32x4*)(cb + (size_t)code * DIM + t * 4);
  float s = v[0]*v[0] + v[1]*v[1] + v[2]*v[2] + v[3]*v[3];
  #pragma unroll
  for (int off = 32; off; off >>= 1) s += __shfl_down(s, off);
  __shared__ float part[4];
  if (lane == 0) part[wid] = s;
  __syncthreads();
  if (t == 0) c2[code] = part[0] + part[1] + part[2] + part[3];
}

// ---------------- kernel 0b: f32 -> fp8 e4m3, fragment-order 256x64-tile layout ----------------
// COALESCED-READ version (R16 post-mortem: old lane->row mapping scattered reads
// over 4KB-strided rows, ~2x read inflation). Thread = source-linear: reads 16
// consecutive f32 (64B, coalesced); writes one 16B chunk to fragment-order slot
// (scatter absorbed by L2; write volume 16.8 MB).
// Output layout identical to R11/R15/R16 (absmax-0-verified): chunk w=st*128+h*64+l
// holds row st*32+(l&31), k-bytes (l>>5)*32+h*16..+16. Inverse map used here:
// src (row r, group j): st=r>>5, h=j&1, l=(r&31)+32*(j>>1).
__global__ __launch_bounds__(256) void convert_fp8_mxc(const float* __restrict__ src,
                                                       uchar* __restrict__ dst) {
  const int c  = blockIdx.x * 256 + threadIdx.x;   // source 64B-group id, [0, 2^20)
  const int q   = c & 1023;          // group within tile
  const int kt  = (c >> 10) & 15;
  const int m   = c >> 14;
  const int r   = q >> 2;            // source row 0..255
  const int j   = q & 3;             // 16-f32 group along k
  const float* s = src + (size_t)(m * 256 + r) * DIM + kt * 64 + j * 16;
  uint64_t lo = 0, hi = 0;
  #pragma unroll
  for (int jj = 0; jj < 8; ++jj) {
    __hip_fp8_e4m3 a(s[jj]);
    __hip_fp8_e4m3 b(s[jj + 8]);
    lo |= (uint64_t)a.__x << (8 * jj);
    hi |= (uint64_t)b.__x << (8 * jj);
  }
  const int st = r >> 5;
  const int h  = j & 1;
  const int l  = (r & 31) + 32 * (j >> 1);
  const size_t wch = (size_t)(m * 16 + kt) * 1024 + st * 128 + h * 64 + l;
  uint64_t* o = (uint64_t*)(dst + wch * 16);
  o[0] = lo; o[1] = hi;
}

// ---------------- kernel 1: 256^2 fp8 32x32x64 GEMM (AGPR acc), 3-deep rings + counted vmcnt ----------------
// Byte-identical to R16 (absmax 0, VGPR 108 + 128 AGPR, no spill, 514 us).
#define STAGE_A(BUF, KT) do {                                                     \
    GLDS16(ga + (KT)*16384,        &lsA[BUF][w*1024]);                            \
    GLDS16(ga + (KT)*16384 + 8192, &lsA[BUF][w*1024 + 8192]);                     \
  } while (0)
#define STAGE_B(BUF, KT) do {                                                     \
    GLDS16(gb + (KT)*16384,        &lsB[BUF][w*1024]);                            \
    GLDS16(gb + (KT)*16384 + 8192, &lsB[BUF][w*1024 + 8192]);                     \
  } while (0)

#define RD_A(BUF) do {                                                            \
    _Pragma("unroll")                                                             \
    for (int mi_ = 0; mi_ < 4; ++mi_) {                                           \
      i32x4 lo_ = *(const i32x4*)(Abase[BUF] + mi_ * 2048);                       \
      i32x4 hi_ = *(const i32x4*)(Abase[BUF] + mi_ * 2048 + 1024);                \
      _Pragma("unroll")                                                           \
      for (int j_ = 0; j_ < 4; ++j_) { aF[mi_][j_] = lo_[j_]; aF[mi_][4+j_] = hi_[j_]; } \
    } } while (0)
#define RD_B(BUF) do {                                                            \
    _Pragma("unroll")                                                             \
    for (int nb_ = 0; nb_ < 2; ++nb_) {                                           \
      i32x4 lo_ = *(const i32x4*)(Bbase[BUF] + nb_ * 2048);                       \
      i32x4 hi_ = *(const i32x4*)(Bbase[BUF] + nb_ * 2048 + 1024);                \
      _Pragma("unroll")                                                           \
      for (int j_ = 0; j_ < 4; ++j_) { bF[nb_][j_] = lo_[j_]; bF[nb_][4+j_] = hi_[j_]; } \
    } } while (0)

#define MMA_ALL do {                                                              \
    __builtin_amdgcn_s_setprio(1);                                                \
    _Pragma("unroll")                                                             \
    for (int mi_ = 0; mi_ < 4; ++mi_) {                                           \
      _Pragma("unroll")                                                           \
      for (int nb_ = 0; nb_ < 2; ++nb_)                                           \
        asm("v_mfma_f32_32x32x64_f8f6f4 %0, %1, %2, %3"                           \
            : "=a"(acc[mi_][nb_])                                                 \
            : "v"(aF[mi_]), "v"(bF[nb_]), "0"(acc[mi_][nb_]));                    \
    }                                                                             \
    __builtin_amdgcn_s_setprio(0);                                                \
  } while (0)

#define G4  asm volatile("s_waitcnt vmcnt(4)" ::: "memory")
#define G0  asm volatile("s_waitcnt vmcnt(0)" ::: "memory")
#define NOG do {} while (0)

#define TILE(KT, CUR, NXT, DOST, GUARD) do {                                      \
    if (DOST) { STAGE_A(NXT, (KT) + 2); STAGE_B(NXT, (KT) + 2); }                 \
    RD_B(CUR);                                                                    \
    RD_A(CUR);                                                                    \
    MMA_ALL;                                                                      \
    asm volatile("s_waitcnt lgkmcnt(0)" ::: "memory");                            \
    GUARD;                                                                        \
    sbar();                                                                       \
  } while (0)

__global__ __launch_bounds__(512, 2) void snap_gemm256(const uchar* __restrict__ xs,
                                                       const uchar* __restrict__ cs,
                                                       const float* __restrict__ c2,
                                                       int* __restrict__ cand) {
  __shared__ uchar lsA[3][16384];   // 3-deep A ring (48 KB)
  __shared__ uchar lsB[3][16384];   // 3-deep B ring (48 KB) -> 96 KB

  const int t    = threadIdx.x;
  const int lane = t & 63;
  const int w    = t >> 6;          // 0..7
  const int wm   = w >> 2;          // 0..1  (rows wm*128..+128)
  const int wn   = w & 3;           // 0..3  (cols wn*64..+64)

  // XCD-aware swizzle (bijective: 4096 % 8 == 0)
  const int bid = blockIdx.x;
  const int swz = (bid & 7) * 512 + (bid >> 3);
  const int bm  = swz & 63;
  const int bn  = swz >> 6;

  const uchar* ga = xs + (size_t)bm * 16 * 16384 + w * 1024 + lane * 16;
  const uchar* gb = cs + (size_t)bn * 16 * 16384 + w * 1024 + lane * 16;

  // Fragment read bases: subtile*2048 + h*1024 + lane*16 (lane-stride 16B: bank-uniform).
  const uchar* Abase[3]; const uchar* Bbase[3];
  #pragma unroll
  for (int b = 0; b < 3; ++b) {
    Abase[b] = &lsA[b][wm * 8192 + lane * 16];
    Bbase[b] = &lsB[b][wn * 4096 + lane * 16];
  }

  f32x16 acc[4][2];
  #pragma unroll
  for (int mi = 0; mi < 4; ++mi)
    #pragma unroll
    for (int nb = 0; nb < 2; ++nb)
      #pragma unroll
      for (int r = 0; r < 16; ++r)
        acc[mi][nb][r] = 0.f;

  i32x8 aF[4], bF[2];

  // ---- prologue: tiles 0 and 1 (8 loads); drain tile 0's 4, keep tile 1's flying ----
  STAGE_A(0, 0); STAGE_B(0, 0);
  STAGE_A(1, 1); STAGE_B(1, 1);
  G4;
  sbar();

  // buf = kt%3; stage target (kt+2)%3. Guard vmcnt(4): drains tile (t+1)'s
  // loads, keeps tile (t+2)'s 4 in flight.
  TILE(0 , 0, 2, 1, G4);
  TILE(1 , 1, 0, 1, G4);
  TILE(2 , 2, 1, 1, G4);
  TILE(3 , 0, 2, 1, G4);
  TILE(4 , 1, 0, 1, G4);
  TILE(5 , 2, 1, 1, G4);
  TILE(6 , 0, 2, 1, G4);
  TILE(7 , 1, 0, 1, G4);
  TILE(8 , 2, 1, 1, G4);
  TILE(9 , 0, 2, 1, G4);
  TILE(10, 1, 0, 1, G4);
  TILE(11, 2, 1, 1, G4);
  TILE(12, 0, 2, 1, G4);
  TILE(13, 1, 0, 1, G4);
  TILE(14, 2, 1, 0, G0);
  TILE(15, 0, 1, 0, NOG);

  __syncthreads();   // full drain before overlaying redbuf on lsA

  // ---- epilogue: per-row top-2 over this block's 256 columns ----
  // C/D 32x32: col = lane&31, row_in = (reg&3) + 8*(reg>>2) + 4*(lane>>5).
  int* red = (int*)&lsA[0][0];   // [4][256][2] i32 = 8 KB
  const int colb = bn * 256 + wn * 64 + (lane & 31);
  const float c2v0 = c2[colb];
  const float c2v1 = c2[colb + 32];
  const int rbase = wm * 128 + 4 * (lane >> 5);

  #pragma unroll
  for (int mi = 0; mi < 4; ++mi) {
    #pragma unroll
    for (int reg = 0; reg < 16; ++reg) {
      int ka = packKey32(fmaf(-2.0f, acc[mi][0][reg], c2v0), colb);
      int kb = packKey32(fmaf(-2.0f, acc[mi][1][reg], c2v1), colb + 32);
      int k1 = imin(ka, kb), k2 = imax(ka, kb);
      #pragma unroll
      for (int m = 1; m < 32; m <<= 1) {
        int o1 = __shfl_xor(k1, m);
        int o2 = __shfl_xor(k2, m);
        int n1 = imin(k1, o1);
        int n2 = imin(imax(k1, o1), imin(k2, o2));
        k1 = n1; k2 = n2;
      }
      if ((lane & 31) == 0) {
        int row = rbase + mi * 32 + (reg & 3) + 8 * (reg >> 2);
        red[(wn * 256 + row) * 2 + 0] = k1;
        red[(wn * 256 + row) * 2 + 1] = k2;
      }
    }
  }
  __syncthreads();

  if (t < 256) {
    int k1 = red[(0 * 256 + t) * 2 + 0];
    int k2 = red[(0 * 256 + t) * 2 + 1];
    #pragma unroll
    for (int q = 1; q < 4; ++q) {
      int p1 = red[(q * 256 + t) * 2 + 0];
      int p2 = red[(q * 256 + t) * 2 + 1];
      int n1 = imin(k1, p1);
      int n2 = imin(imax(k1, p1), imin(k2, p2));
      k1 = n1; k2 = n2;
    }
    size_t o = (size_t)(bm * 256 + t) * 128 + (size_t)bn * 2;
    cand[o]     = k1;
    cand[o + 1] = k2;
  }
}

// ---------------- kernel 1 (fallback, known-good structure): on-the-fly bf16 128^2 ----------------
__global__ __launch_bounds__(256) void snap_gemm_slow(const float* __restrict__ x,
                                                      const float* __restrict__ cb,
                                                      const float* __restrict__ c2,
                                                      int* __restrict__ cand) {
  __shared__ ushort lsA[2][8192];
  __shared__ ushort lsB[2][8192];
  __shared__ int redbuf[2][128][2];

  const int t    = threadIdx.x;
  const int lane = t & 63;
  const int wid  = t >> 6;
  const int wm   = wid & 1;
  const int wn   = wid >> 1;
  const int l15  = lane & 15;
  const int kgrp = lane >> 4;

  const int bm = blockIdx.x & 127;
  const int bn = blockIdx.x >> 7;
  const int rowBase = bm * 128;
  const int colBase = bn * 128;

  const float* aptr[4];
  const float* bptr[4];
  int ldsOff[4];
  #pragma unroll
  for (int i = 0; i < 4; ++i) {
    int pc = t + 256 * i;
    int row = pc >> 3;
    int g = (pc & 7) ^ (row & 7);
    aptr[i] = x  + (size_t)(rowBase + row) * DIM + g * 8;
    bptr[i] = cb + (size_t)(colBase + row) * DIM + g * 8;
    ldsOff[i] = pc * 8;
  }

  f32x4 acc[4][4];
  #pragma unroll
  for (int mi = 0; mi < 4; ++mi)
    #pragma unroll
    for (int ni = 0; ni < 4; ++ni)
      acc[mi][ni] = (f32x4){0.f, 0.f, 0.f, 0.f};

  auto STAGE = [&](int buf, int kt) {
    const int kOff = kt * 64;
    #pragma unroll
    for (int i = 0; i < 4; ++i) {
      f32x4 a0 = *(const f32x4*)(aptr[i] + kOff);
      f32x4 a1 = *(const f32x4*)(aptr[i] + kOff + 4);
      f32x4 b0 = *(const f32x4*)(bptr[i] + kOff);
      f32x4 b1 = *(const f32x4*)(bptr[i] + kOff + 4);
      bf16x8 pa, pb;
      #pragma unroll
      for (int j = 0; j < 4; ++j) {
        pa[j]     = (short)f2bf(a0[j]);
        pa[j + 4] = (short)f2bf(a1[j]);
        pb[j]     = (short)f2bf(b0[j]);
        pb[j + 4] = (short)f2bf(b1[j]);
      }
      *(bf16x8*)(&lsA[buf][ldsOff[i]]) = pa;
      *(bf16x8*)(&lsB[buf][ldsOff[i]]) = pb;
    }
  };

  STAGE(0, 0);
  __syncthreads();

  for (int kt = 0; kt < DIM / 64; ++kt) {
    const int cur = kt & 1;
    if (kt < DIM / 64 - 1) STAGE(cur ^ 1, kt + 1);

    const ushort* bA = &lsA[cur][0];
    const ushort* bB = &lsB[cur][0];
    #pragma unroll
    for (int ks = 0; ks < 2; ++ks) {
      const int gidx = ks * 4 + kgrp;
      bf16x8 af[4], bfr[4];
      #pragma unroll
      for (int mi = 0; mi < 4; ++mi) {
        int r_ = wm * 64 + mi * 16 + l15;
        af[mi] = *(const bf16x8*)(bA + (r_ * 8 + (gidx ^ (r_ & 7))) * 8);
      }
      #pragma unroll
      for (int ni = 0; ni < 4; ++ni) {
        int c_ = wn * 64 + ni * 16 + l15;
        bfr[ni] = *(const bf16x8*)(bB + (c_ * 8 + (gidx ^ (c_ & 7))) * 8);
      }
      #pragma unroll
      for (int mi = 0; mi < 4; ++mi)
        #pragma unroll
        for (int ni = 0; ni < 4; ++ni)
          acc[mi][ni] = __builtin_amdgcn_mfma_f32_16x16x32_bf16(af[mi], bfr[ni], acc[mi][ni], 0, 0, 0);
    }
    __syncthreads();
  }

  float c2v[4];
  int   colv[4];
  #pragma unroll
  for (int ni = 0; ni < 4; ++ni) {
    colv[ni] = colBase + wn * 64 + ni * 16 + l15;
    c2v[ni]  = c2[colv[ni]];
  }

  #pragma unroll
  for (int mi = 0; mi < 4; ++mi) {
    #pragma unroll
    for (int r = 0; r < 4; ++r) {
      int a = packKey32(fmaf(-2.0f, acc[mi][0][r], c2v[0]), colv[0]);
      int b = packKey32(fmaf(-2.0f, acc[mi][1][r], c2v[1]), colv[1]);
      int c = packKey32(fmaf(-2.0f, acc[mi][2][r], c2v[2]), colv[2]);
      int d = packKey32(fmaf(-2.0f, acc[mi][3][r], c2v[3]), colv[3]);
      int lo1 = imin(a, b), hi1 = imax(a, b);
      int lo2 = imin(c, d), hi2 = imax(c, d);
      int k1 = imin(lo1, lo2);
      int k2 = imin(imax(lo1, lo2), imin(hi1, hi2));
      #pragma unroll
      for (int m = 1; m < 16; m <<= 1) {
        int o1 = __shfl_xor(k1, m);
        int o2 = __shfl_xor(k2, m);
        int n1 = imin(k1, o1);
        int n2 = imin(imax(k1, o1), imin(k2, o2));
        k1 = n1; k2 = n2;
      }
      if (l15 == 0) {
        int rl = wm * 64 + mi * 16 + kgrp * 4 + r;
        redbuf[wn][rl][0] = k1;
        redbuf[wn][rl][1] = k2;
      }
    }
  }
  __syncthreads();

  if (t < 128) {
    int a1 = redbuf[0][t][0], a2 = redbuf[0][t][1];
    int b1 = redbuf[1][t][0], b2 = redbuf[1][t][1];
    int m1 = imin(a1, b1);
    int m2 = imin(imax(a1, b1), imin(a2, b2));
    size_t o = (size_t)(rowBase + t) * 256 + (size_t)bn * 2;
    cand[o]     = m1;
    cand[o + 1] = m2;
  }
}

// ---------------- kernel 2: exact f64 rerank of candidates within margin of pool-min ----------------
__global__ __launch_bounds__(256) void rerank(const float* __restrict__ x,
                                              const float* __restrict__ cb,
                                              const int* __restrict__ cand,
                                              int* __restrict__ bestidx,
                                              int poolN) {
  const int row = blockIdx.x;
  const int t = threadIdx.x, lane = t & 63, wid = t >> 6;
  __shared__ int    smin[4];
  __shared__ int    gshared;
  __shared__ double dpart[4];
  __shared__ int    cnt;
  __shared__ int    list[64];

  int my = (t < poolN) ? cand[(size_t)row * poolN + t] : 0x7FFFFFFF;
  int k = my;
  #pragma unroll
  for (int off = 32; off; off >>= 1) k = imin(k, __shfl_down(k, off));
  if (lane == 0) smin[wid] = k;
  if (t == 0) cnt = 0;
  __syncthreads();
  if (t == 0) {
    int g = smin[0];
    for (int i = 1; i < 4; ++i) g = imin(g, smin[i]);
    gshared = g;
  }
  __syncthreads();

  const int gq = gshared >> 14;
  if ((my >> 14) <= gq + MARGIN_Q) {
    int p = atomicAdd(&cnt, 1);
    if (p < 64) list[p] = my & 16383;
  }
  __syncthreads();
  int n = cnt; if (n > 64) n = 64;

  uint64_t best = ~0ull;
  const float* xr = x + (size_t)row * DIM;
  for (int i = 0; i < n; ++i) {
    const int cidx = list[i];
    const float* cr = cb + (size_t)cidx * DIM;
    double p = 0.0;
    #pragma unroll
    for (int j = 0; j < 4; ++j) {
      int d = t + 256 * j;
      double diff = (double)xr[d] - (double)cr[d];
      p += diff * diff;
    }
    #pragma unroll
    for (int off = 32; off; off >>= 1) p += __shfl_down(p, off);
    if (lane == 0) dpart[wid] = p;
    __syncthreads();
    if (t == 0) {
      double d2 = dpart[0] + dpart[1] + dpart[2] + dpart[3];
      uint64_t bits = (uint64_t)__double_as_longlong(d2);
      uint64_t key = (bits & ~0x3FFFull) | (uint32_t)cidx;
      if (key < best) best = key;
    }
    __syncthreads();
  }
  if (t == 0) bestidx[row] = (int)(best & 0x3FFFull);
}

// ---------------- kernel 3: gather winning codebook rows ----------------
__global__ __launch_bounds__(256) void gather_rows(const float* __restrict__ cb,
                                                   const int* __restrict__ bestidx,
                                                   float* __restrict__ out) {
  const int row = blockIdx.x;
  const int idx = bestidx[row];
  f32x4 v = *(const f32x4*)(cb + (size_t)idx * DIM + threadIdx.x * 4);
  *(f32x4*)(out + (size_t)row * DIM + threadIdx.x * 4) = v;
}

extern "C" void kernel_launch(void* const* d_in, const int* in_sizes, int n_in,
                              void* d_out, int out_size, void* d_ws, size_t ws_size,
                              hipStream_t stream) {
  const float* x  = (const float*)d_in[0];
  const float* cb = (const float*)d_in[1];
  float* out = (float*)d_out;

  float* c2      = (float*)d_ws;                        // 64 KB
  int*   bestidx = (int*)((char*)d_ws + 64 * 1024);     // 64 KB

  const size_t candBytes = (size_t)NROWS * 128 * 4;     // 8 MB (32-bit keys)
  const size_t needFast  = 128 * 1024 + candBytes;

  c2_kernel<<<NCODES, 256, 0, stream>>>(cb, c2);

  if (ws_size >= needFast) {
    uchar* xs = (uchar*)d_out;                          // 16.8 MB fp8, fragment-order
    uchar* cs = xs + (size_t)NROWS * DIM;               // 16.8 MB
    int* cand = (int*)((char*)d_ws + 128 * 1024);

    convert_fp8_mxc<<<4096, 256, 0, stream>>>(x,  xs);
    convert_fp8_mxc<<<4096, 256, 0, stream>>>(cb, cs);
    snap_gemm256<<<4096, 512, 0, stream>>>(xs, cs, c2, cand);
    rerank<<<NROWS, 256, 0, stream>>>(x, cb, cand, bestidx, 128);
    gather_rows<<<NROWS, 256, 0, stream>>>(cb, bestidx, out);
  } else {
    int* cand = (int*)d_out;
    snap_gemm_slow<<<(NROWS / 128) * (NCODES / 128), 256, 0, stream>>>(x, cb, c2, cand);
    rerank<<<NROWS, 256, 0, stream>>>(x, cb, cand, bestidx, 256);
    gather_rows<<<NROWS, 256, 0, stream>>>(cb, bestidx, out);
  }
}

// Round 18
// 611.052 us; speedup vs baseline: 1.0364x; 1.0296x over previous
//
#include <hip/hip_runtime.h>
#include <hip/hip_bf16.h>
#include <hip/hip_fp8.h>
#include <stdint.h>

// x: (4,4096,1024) f32 -> 16384 x 1024 rows; codebook: (16384,1024) f32
#define NROWS  16384
#define NCODES 16384
#define DIM    1024
#define MARGIN_Q 514        // fp8 path: 32.1 in 1/16 units (~9 sigma of fp8 score noise)

typedef float f32x4   __attribute__((ext_vector_type(4)));
typedef float f32x16  __attribute__((ext_vector_type(16)));
typedef int   i32x4   __attribute__((ext_vector_type(4)));
typedef int   i32x8   __attribute__((ext_vector_type(8)));
typedef short bf16x8  __attribute__((ext_vector_type(8)));
typedef unsigned char uchar;

__device__ __forceinline__ ushort f2bf(float f) {
  uint32_t u = __float_as_uint(f);
  uint32_t r = u + 0x7FFFu + ((u >> 16) & 1u);
  return (ushort)(r >> 16);
}
__device__ __forceinline__ int imin(int a, int b){ return a < b ? a : b; }
__device__ __forceinline__ int imax(int a, int b){ return a < b ? b : a; }
__device__ __forceinline__ int packKey32(float s, int idx) {
  int q = (int)rintf(s * 16.0f);
  return q * 16384 + idx;
}

#define GLDS16(gp, lp) \
  __builtin_amdgcn_global_load_lds((const __attribute__((address_space(1))) void*)(gp), \
                                   (__attribute__((address_space(3))) void*)(lp), 16, 0, 0)

__device__ __forceinline__ void sbar() {
  asm volatile("" ::: "memory");
  __builtin_amdgcn_s_barrier();
  asm volatile("" ::: "memory");
}

// ---------------- kernel 0: c2[c] = sum(codebook[c]^2) (exact f32) ----------------
__global__ __launch_bounds__(256) void c2_kernel(const float* __restrict__ cb,
                                                 float* __restrict__ c2) {
  const int code = blockIdx.x;
  const int t = threadIdx.x, lane = t & 63, wid = t >> 6;
  f32x4 v = *(const f32x4*)(cb + (size_t)code * DIM + t * 4);
  float s = v[0]*v[0] + v[1]*v[1] + v[2]*v[2] + v[3]*v[3];
  #pragma unroll
  for (int off = 32; off; off >>= 1) s += __shfl_down(s, off);
  __shared__ float part[4];
  if (lane == 0) part[wid] = s;
  __syncthreads();
  if (t == 0) c2[code] = part[0] + part[1] + part[2] + part[3];
}

// ---------------- kernel 0b: f32 -> fp8 e4m3, fragment-order 256x64-tile layout ----------------
// Coalesced-read converter (R17). Output layout identical to R11/R15-R17
// (absmax-0-verified): per 16KB kt-tile, chunk w=st*128+h*64+l holds row
// st*32+(l&31), k-bytes (l>>5)*32+h*16..+16.
__global__ __launch_bounds__(256) void convert_fp8_mxc(const float* __restrict__ src,
                                                       uchar* __restrict__ dst) {
  const int c  = blockIdx.x * 256 + threadIdx.x;   // source 64B-group id, [0, 2^20)
  const int q   = c & 1023;
  const int kt  = (c >> 10) & 15;
  const int m   = c >> 14;
  const int r   = q >> 2;
  const int j   = q & 3;
  const float* s = src + (size_t)(m * 256 + r) * DIM + kt * 64 + j * 16;
  uint64_t lo = 0, hi = 0;
  #pragma unroll
  for (int jj = 0; jj < 8; ++jj) {
    __hip_fp8_e4m3 a(s[jj]);
    __hip_fp8_e4m3 b(s[jj + 8]);
    lo |= (uint64_t)a.__x << (8 * jj);
    hi |= (uint64_t)b.__x << (8 * jj);
  }
  const int st = r >> 5;
  const int h  = j & 1;
  const int l  = (r & 31) + 32 * (j >> 1);
  const size_t wch = (size_t)(m * 16 + kt) * 1024 + st * 128 + h * 64 + l;
  uint64_t* o = (uint64_t*)(dst + wch * 16);
  o[0] = lo; o[1] = hi;
}

// ---------------- kernel 1: 256^2 fp8 32x32x64 GEMM, BK=128 super-tiles ----------------
// R17 post-mortem: ~2400 cyc/K-tile FIXED overhead (barrier+waitcnt+issue) vs
// ~1100 MFMA. BK=128 super-tile = 2 consecutive kt-tiles per phase: 16 MFMAs,
// ONE lgkm/vmcnt/barrier per phase -> overhead amortized 2x. 8 phases. LDS
// 2x(32K A + 32K B) = 128 KB (1 block/CU, already the case). Regs unchanged.
#define STAGE_A(BUF, KT2) do {                                                    \
    GLDS16(ga + (KT2)*32768,         &lsA[BUF][w*1024]);                          \
    GLDS16(ga + (KT2)*32768 +  8192, &lsA[BUF][w*1024 +  8192]);                  \
    GLDS16(ga + (KT2)*32768 + 16384, &lsA[BUF][w*1024 + 16384]);                  \
    GLDS16(ga + (KT2)*32768 + 24576, &lsA[BUF][w*1024 + 24576]);                  \
  } while (0)
#define STAGE_B(BUF, KT2) do {                                                    \
    GLDS16(gb + (KT2)*32768,         &lsB[BUF][w*1024]);                          \
    GLDS16(gb + (KT2)*32768 +  8192, &lsB[BUF][w*1024 +  8192]);                  \
    GLDS16(gb + (KT2)*32768 + 16384, &lsB[BUF][w*1024 + 16384]);                  \
    GLDS16(gb + (KT2)*32768 + 24576, &lsB[BUF][w*1024 + 24576]);                  \
  } while (0)

#define RD_A(BUF, H) do {                                                         \
    _Pragma("unroll")                                                             \
    for (int mi_ = 0; mi_ < 4; ++mi_) {                                           \
      i32x4 lo_ = *(const i32x4*)(Abase[BUF] + (H)*16384 + mi_ * 2048);           \
      i32x4 hi_ = *(const i32x4*)(Abase[BUF] + (H)*16384 + mi_ * 2048 + 1024);    \
      _Pragma("unroll")                                                           \
      for (int j_ = 0; j_ < 4; ++j_) { aF[mi_][j_] = lo_[j_]; aF[mi_][4+j_] = hi_[j_]; } \
    } } while (0)
#define RD_B(BUF, H) do {                                                         \
    _Pragma("unroll")                                                             \
    for (int nb_ = 0; nb_ < 2; ++nb_) {                                           \
      i32x4 lo_ = *(const i32x4*)(Bbase[BUF] + (H)*16384 + nb_ * 2048);           \
      i32x4 hi_ = *(const i32x4*)(Bbase[BUF] + (H)*16384 + nb_ * 2048 + 1024);    \
      _Pragma("unroll")                                                           \
      for (int j_ = 0; j_ < 4; ++j_) { bF[nb_][j_] = lo_[j_]; bF[nb_][4+j_] = hi_[j_]; } \
    } } while (0)

#define MMA_ALL do {                                                              \
    __builtin_amdgcn_s_setprio(1);                                                \
    _Pragma("unroll")                                                             \
    for (int mi_ = 0; mi_ < 4; ++mi_) {                                           \
      _Pragma("unroll")                                                           \
      for (int nb_ = 0; nb_ < 2; ++nb_)                                           \
        asm("v_mfma_f32_32x32x64_f8f6f4 %0, %1, %2, %3"                           \
            : "=a"(acc[mi_][nb_])                                                 \
            : "v"(aF[mi_]), "v"(bF[nb_]), "0"(acc[mi_][nb_]));                    \
    }                                                                             \
    __builtin_amdgcn_s_setprio(0);                                                \
  } while (0)

#define G0  asm volatile("s_waitcnt vmcnt(0)" ::: "memory")
#define NOG do {} while (0)

// One super-tile, ONE barrier. Stage(t+1) at phase start into the alternate
// buffer (its reads drained at lgkm0+barrier of t-1); G0 at end has a full
// phase of flight; barrier publishes t+1.
#define TILE(KT2, CUR, NXT, DOST, GUARD) do {                                     \
    if (DOST) { STAGE_A(NXT, (KT2) + 1); STAGE_B(NXT, (KT2) + 1); }               \
    RD_B(CUR, 0);                                                                 \
    RD_A(CUR, 0);                                                                 \
    MMA_ALL;                                                                      \
    RD_B(CUR, 1);                                                                 \
    RD_A(CUR, 1);                                                                 \
    MMA_ALL;                                                                      \
    asm volatile("s_waitcnt lgkmcnt(0)" ::: "memory");                            \
    GUARD;                                                                        \
    sbar();                                                                       \
  } while (0)

__global__ __launch_bounds__(512, 2) void snap_gemm256(const uchar* __restrict__ xs,
                                                       const uchar* __restrict__ cs,
                                                       const float* __restrict__ c2,
                                                       int* __restrict__ cand) {
  __shared__ uchar lsA[2][32768];   // 2-deep A, 32 KB each (BK=128)
  __shared__ uchar lsB[2][32768];   // 2-deep B -> 128 KB total

  const int t    = threadIdx.x;
  const int lane = t & 63;
  const int w    = t >> 6;          // 0..7
  const int wm   = w >> 2;          // 0..1  (rows wm*128..+128)
  const int wn   = w & 3;           // 0..3  (cols wn*64..+64)

  // XCD-aware swizzle (bijective: 4096 % 8 == 0)
  const int bid = blockIdx.x;
  const int swz = (bid & 7) * 512 + (bid >> 3);
  const int bm  = swz & 63;
  const int bn  = swz >> 6;

  const uchar* ga = xs + (size_t)bm * 16 * 16384 + w * 1024 + lane * 16;
  const uchar* gb = cs + (size_t)bn * 16 * 16384 + w * 1024 + lane * 16;

  // Fragment read bases (lane-stride 16B: bank-uniform). Half H at +H*16384.
  const uchar* Abase[2]; const uchar* Bbase[2];
  #pragma unroll
  for (int b = 0; b < 2; ++b) {
    Abase[b] = &lsA[b][wm * 8192 + lane * 16];
    Bbase[b] = &lsB[b][wn * 4096 + lane * 16];
  }

  f32x16 acc[4][2];
  #pragma unroll
  for (int mi = 0; mi < 4; ++mi)
    #pragma unroll
    for (int nb = 0; nb < 2; ++nb)
      #pragma unroll
      for (int r = 0; r < 16; ++r)
        acc[mi][nb][r] = 0.f;

  i32x8 aF[4], bF[2];

  // ---- prologue: super-tile 0 (8 loads) ----
  STAGE_A(0, 0); STAGE_B(0, 0);
  G0;
  sbar();

  TILE(0, 0, 1, 1, G0);
  TILE(1, 1, 0, 1, G0);
  TILE(2, 0, 1, 1, G0);
  TILE(3, 1, 0, 1, G0);
  TILE(4, 0, 1, 1, G0);
  TILE(5, 1, 0, 1, G0);
  TILE(6, 0, 1, 1, G0);
  TILE(7, 1, 0, 0, NOG);

  __syncthreads();   // full drain before overlaying redbuf on lsA

  // ---- epilogue: per-row top-2 over this block's 256 columns ----
  // C/D 32x32: col = lane&31, row_in = (reg&3) + 8*(reg>>2) + 4*(lane>>5).
  int* red = (int*)&lsA[0][0];   // [4][256][2] i32 = 8 KB
  const int colb = bn * 256 + wn * 64 + (lane & 31);
  const float c2v0 = c2[colb];
  const float c2v1 = c2[colb + 32];
  const int rbase = wm * 128 + 4 * (lane >> 5);

  #pragma unroll
  for (int mi = 0; mi < 4; ++mi) {
    #pragma unroll
    for (int reg = 0; reg < 16; ++reg) {
      int ka = packKey32(fmaf(-2.0f, acc[mi][0][reg], c2v0), colb);
      int kb = packKey32(fmaf(-2.0f, acc[mi][1][reg], c2v1), colb + 32);
      int k1 = imin(ka, kb), k2 = imax(ka, kb);
      #pragma unroll
      for (int m = 1; m < 32; m <<= 1) {
        int o1 = __shfl_xor(k1, m);
        int o2 = __shfl_xor(k2, m);
        int n1 = imin(k1, o1);
        int n2 = imin(imax(k1, o1), imin(k2, o2));
        k1 = n1; k2 = n2;
      }
      if ((lane & 31) == 0) {
        int row = rbase + mi * 32 + (reg & 3) + 8 * (reg >> 2);
        red[(wn * 256 + row) * 2 + 0] = k1;
        red[(wn * 256 + row) * 2 + 1] = k2;
      }
    }
  }
  __syncthreads();

  if (t < 256) {
    int k1 = red[(0 * 256 + t) * 2 + 0];
    int k2 = red[(0 * 256 + t) * 2 + 1];
    #pragma unroll
    for (int q = 1; q < 4; ++q) {
      int p1 = red[(q * 256 + t) * 2 + 0];
      int p2 = red[(q * 256 + t) * 2 + 1];
      int n1 = imin(k1, p1);
      int n2 = imin(imax(k1, p1), imin(k2, p2));
      k1 = n1; k2 = n2;
    }
    size_t o = (size_t)(bm * 256 + t) * 128 + (size_t)bn * 2;
    cand[o]     = k1;
    cand[o + 1] = k2;
  }
}

// ---------------- kernel 1 (fallback, known-good structure): on-the-fly bf16 128^2 ----------------
__global__ __launch_bounds__(256) void snap_gemm_slow(const float* __restrict__ x,
                                                      const float* __restrict__ cb,
                                                      const float* __restrict__ c2,
                                                      int* __restrict__ cand) {
  __shared__ ushort lsA[2][8192];
  __shared__ ushort lsB[2][8192];
  __shared__ int redbuf[2][128][2];

  const int t    = threadIdx.x;
  const int lane = t & 63;
  const int wid  = t >> 6;
  const int wm   = wid & 1;
  const int wn   = wid >> 1;
  const int l15  = lane & 15;
  const int kgrp = lane >> 4;

  const int bm = blockIdx.x & 127;
  const int bn = blockIdx.x >> 7;
  const int rowBase = bm * 128;
  const int colBase = bn * 128;

  const float* aptr[4];
  const float* bptr[4];
  int ldsOff[4];
  #pragma unroll
  for (int i = 0; i < 4; ++i) {
    int pc = t + 256 * i;
    int row = pc >> 3;
    int g = (pc & 7) ^ (row & 7);
    aptr[i] = x  + (size_t)(rowBase + row) * DIM + g * 8;
    bptr[i] = cb + (size_t)(colBase + row) * DIM + g * 8;
    ldsOff[i] = pc * 8;
  }

  f32x4 acc[4][4];
  #pragma unroll
  for (int mi = 0; mi < 4; ++mi)
    #pragma unroll
    for (int ni = 0; ni < 4; ++ni)
      acc[mi][ni] = (f32x4){0.f, 0.f, 0.f, 0.f};

  auto STAGE = [&](int buf, int kt) {
    const int kOff = kt * 64;
    #pragma unroll
    for (int i = 0; i < 4; ++i) {
      f32x4 a0 = *(const f32x4*)(aptr[i] + kOff);
      f32x4 a1 = *(const f32x4*)(aptr[i] + kOff + 4);
      f32x4 b0 = *(const f32x4*)(bptr[i] + kOff);
      f32x4 b1 = *(const f32x4*)(bptr[i] + kOff + 4);
      bf16x8 pa, pb;
      #pragma unroll
      for (int j = 0; j < 4; ++j) {
        pa[j]     = (short)f2bf(a0[j]);
        pa[j + 4] = (short)f2bf(a1[j]);
        pb[j]     = (short)f2bf(b0[j]);
        pb[j + 4] = (short)f2bf(b1[j]);
      }
      *(bf16x8*)(&lsA[buf][ldsOff[i]]) = pa;
      *(bf16x8*)(&lsB[buf][ldsOff[i]]) = pb;
    }
  };

  STAGE(0, 0);
  __syncthreads();

  for (int kt = 0; kt < DIM / 64; ++kt) {
    const int cur = kt & 1;
    if (kt < DIM / 64 - 1) STAGE(cur ^ 1, kt + 1);

    const ushort* bA = &lsA[cur][0];
    const ushort* bB = &lsB[cur][0];
    #pragma unroll
    for (int ks = 0; ks < 2; ++ks) {
      const int gidx = ks * 4 + kgrp;
      bf16x8 af[4], bfr[4];
      #pragma unroll
      for (int mi = 0; mi < 4; ++mi) {
        int r_ = wm * 64 + mi * 16 + l15;
        af[mi] = *(const bf16x8*)(bA + (r_ * 8 + (gidx ^ (r_ & 7))) * 8);
      }
      #pragma unroll
      for (int ni = 0; ni < 4; ++ni) {
        int c_ = wn * 64 + ni * 16 + l15;
        bfr[ni] = *(const bf16x8*)(bB + (c_ * 8 + (gidx ^ (c_ & 7))) * 8);
      }
      #pragma unroll
      for (int mi = 0; mi < 4; ++mi)
        #pragma unroll
        for (int ni = 0; ni < 4; ++ni)
          acc[mi][ni] = __builtin_amdgcn_mfma_f32_16x16x32_bf16(af[mi], bfr[ni], acc[mi][ni], 0, 0, 0);
    }
    __syncthreads();
  }

  float c2v[4];
  int   colv[4];
  #pragma unroll
  for (int ni = 0; ni < 4; ++ni) {
    colv[ni] = colBase + wn * 64 + ni * 16 + l15;
    c2v[ni]  = c2[colv[ni]];
  }

  #pragma unroll
  for (int mi = 0; mi < 4; ++mi) {
    #pragma unroll
    for (int r = 0; r < 4; ++r) {
      int a = packKey32(fmaf(-2.0f, acc[mi][0][r], c2v[0]), colv[0]);
      int b = packKey32(fmaf(-2.0f, acc[mi][1][r], c2v[1]), colv[1]);
      int c = packKey32(fmaf(-2.0f, acc[mi][2][r], c2v[2]), colv[2]);
      int d = packKey32(fmaf(-2.0f, acc[mi][3][r], c2v[3]), colv[3]);
      int lo1 = imin(a, b), hi1 = imax(a, b);
      int lo2 = imin(c, d), hi2 = imax(c, d);
      int k1 = imin(lo1, lo2);
      int k2 = imin(imax(lo1, lo2), imin(hi1, hi2));
      #pragma unroll
      for (int m = 1; m < 16; m <<= 1) {
        int o1 = __shfl_xor(k1, m);
        int o2 = __shfl_xor(k2, m);
        int n1 = imin(k1, o1);
        int n2 = imin(imax(k1, o1), imin(k2, o2));
        k1 = n1; k2 = n2;
      }
      if (l15 == 0) {
        int rl = wm * 64 + mi * 16 + kgrp * 4 + r;
        redbuf[wn][rl][0] = k1;
        redbuf[wn][rl][1] = k2;
      }
    }
  }
  __syncthreads();

  if (t < 128) {
    int a1 = redbuf[0][t][0], a2 = redbuf[0][t][1];
    int b1 = redbuf[1][t][0], b2 = redbuf[1][t][1];
    int m1 = imin(a1, b1);
    int m2 = imin(imax(a1, b1), imin(a2, b2));
    size_t o = (size_t)(rowBase + t) * 256 + (size_t)bn * 2;
    cand[o]     = m1;
    cand[o + 1] = m2;
  }
}

// ---------------- kernel 2: exact f64 rerank of candidates within margin of pool-min ----------------
__global__ __launch_bounds__(256) void rerank(const float* __restrict__ x,
                                              const float* __restrict__ cb,
                                              const int* __restrict__ cand,
                                              int* __restrict__ bestidx,
                                              int poolN) {
  const int row = blockIdx.x;
  const int t = threadIdx.x, lane = t & 63, wid = t >> 6;
  __shared__ int    smin[4];
  __shared__ int    gshared;
  __shared__ double dpart[4];
  __shared__ int    cnt;
  __shared__ int    list[64];

  int my = (t < poolN) ? cand[(size_t)row * poolN + t] : 0x7FFFFFFF;
  int k = my;
  #pragma unroll
  for (int off = 32; off; off >>= 1) k = imin(k, __shfl_down(k, off));
  if (lane == 0) smin[wid] = k;
  if (t == 0) cnt = 0;
  __syncthreads();
  if (t == 0) {
    int g = smin[0];
    for (int i = 1; i < 4; ++i) g = imin(g, smin[i]);
    gshared = g;
  }
  __syncthreads();

  const int gq = gshared >> 14;
  if ((my >> 14) <= gq + MARGIN_Q) {
    int p = atomicAdd(&cnt, 1);
    if (p < 64) list[p] = my & 16383;
  }
  __syncthreads();
  int n = cnt; if (n > 64) n = 64;

  uint64_t best = ~0ull;
  const float* xr = x + (size_t)row * DIM;
  for (int i = 0; i < n; ++i) {
    const int cidx = list[i];
    const float* cr = cb + (size_t)cidx * DIM;
    double p = 0.0;
    #pragma unroll
    for (int j = 0; j < 4; ++j) {
      int d = t + 256 * j;
      double diff = (double)xr[d] - (double)cr[d];
      p += diff * diff;
    }
    #pragma unroll
    for (int off = 32; off; off >>= 1) p += __shfl_down(p, off);
    if (lane == 0) dpart[wid] = p;
    __syncthreads();
    if (t == 0) {
      double d2 = dpart[0] + dpart[1] + dpart[2] + dpart[3];
      uint64_t bits = (uint64_t)__double_as_longlong(d2);
      uint64_t key = (bits & ~0x3FFFull) | (uint32_t)cidx;
      if (key < best) best = key;
    }
    __syncthreads();
  }
  if (t == 0) bestidx[row] = (int)(best & 0x3FFFull);
}

// ---------------- kernel 3: gather winning codebook rows ----------------
__global__ __launch_bounds__(256) void gather_rows(const float* __restrict__ cb,
                                                   const int* __restrict__ bestidx,
                                                   float* __restrict__ out) {
  const int row = blockIdx.x;
  const int idx = bestidx[row];
  f32x4 v = *(const f32x4*)(cb + (size_t)idx * DIM + threadIdx.x * 4);
  *(f32x4*)(out + (size_t)row * DIM + threadIdx.x * 4) = v;
}

extern "C" void kernel_launch(void* const* d_in, const int* in_sizes, int n_in,
                              void* d_out, int out_size, void* d_ws, size_t ws_size,
                              hipStream_t stream) {
  const float* x  = (const float*)d_in[0];
  const float* cb = (const float*)d_in[1];
  float* out = (float*)d_out;

  float* c2      = (float*)d_ws;                        // 64 KB
  int*   bestidx = (int*)((char*)d_ws + 64 * 1024);     // 64 KB

  const size_t candBytes = (size_t)NROWS * 128 * 4;     // 8 MB (32-bit keys)
  const size_t needFast  = 128 * 1024 + candBytes;

  c2_kernel<<<NCODES, 256, 0, stream>>>(cb, c2);

  if (ws_size >= needFast) {
    uchar* xs = (uchar*)d_out;                          // 16.8 MB fp8, fragment-order
    uchar* cs = xs + (size_t)NROWS * DIM;               // 16.8 MB
    int* cand = (int*)((char*)d_ws + 128 * 1024);

    convert_fp8_mxc<<<4096, 256, 0, stream>>>(x,  xs);
    convert_fp8_mxc<<<4096, 256, 0, stream>>>(cb, cs);
    snap_gemm256<<<4096, 512, 0, stream>>>(xs, cs, c2, cand);
    rerank<<<NROWS, 256, 0, stream>>>(x, cb, cand, bestidx, 128);
    gather_rows<<<NROWS, 256, 0, stream>>>(cb, bestidx, out);
  } else {
    int* cand = (int*)d_out;
    snap_gemm_slow<<<(NROWS / 128) * (NCODES / 128), 256, 0, stream>>>(x, cb, c2, cand);
    rerank<<<NROWS, 256, 0, stream>>>(x, cb, cand, bestidx, 256);
    gather_rows<<<NROWS, 256, 0, stream>>>(cb, bestidx, out);
  }
}